// Round 1
// baseline (3963.239 us; speedup 1.0000x reference)
//
#include <hip/hip_runtime.h>
#include <math.h>

#define N_NODES 100000
#define N_EDGES 3200000
#define N_GRAPHS 1000
#define C 11
#define D 4
#define ZDIM (2*C + D)   // 26
#define BN_EPS 1e-5f

__device__ __forceinline__ float softplusf(float x) {
    return (x > 20.0f) ? x : log1pf(expf(x));
}
__device__ __forceinline__ float sigmoidf(float x) {
    return 1.0f / (1.0f + expf(-x));
}

// ---------------- edge kernel: msg = sigmoid(z@Wf+bf) * softplus(z@Ws+bs); agg[dst] += msg
__global__ void __launch_bounds__(256) edge_kernel(
    const float* __restrict__ x,        // [N, C] node features (input of this layer)
    const int*   __restrict__ ei,       // [2, E]
    const float* __restrict__ ea,       // [E, D]
    const float* __restrict__ Wf, const float* __restrict__ bf,
    const float* __restrict__ Ws, const float* __restrict__ bs,
    float* __restrict__ agg)            // [N, C] pre-zeroed
{
    __shared__ float sWf[ZDIM * C];
    __shared__ float sWs[ZDIM * C];
    __shared__ float sbf[C];
    __shared__ float sbs[C];
    for (int i = threadIdx.x; i < ZDIM * C; i += blockDim.x) {
        sWf[i] = Wf[i];
        sWs[i] = Ws[i];
    }
    if (threadIdx.x < C) { sbf[threadIdx.x] = bf[threadIdx.x]; sbs[threadIdx.x] = bs[threadIdx.x]; }
    __syncthreads();

    int e = blockIdx.x * blockDim.x + threadIdx.x;
    if (e >= N_EDGES) return;

    int src = ei[e];                // edge_index[0][e]
    int dst = ei[N_EDGES + e];      // edge_index[1][e]

    float z[ZDIM];
    #pragma unroll
    for (int j = 0; j < C; ++j) z[j] = x[dst * C + j];        // x_i = x[dst]
    #pragma unroll
    for (int j = 0; j < C; ++j) z[C + j] = x[src * C + j];    // x_j = x[src]
    #pragma unroll
    for (int j = 0; j < D; ++j) z[2 * C + j] = ea[e * D + j];

    #pragma unroll
    for (int c = 0; c < C; ++c) {
        float f = sbf[c];
        float s = sbs[c];
        #pragma unroll
        for (int k = 0; k < ZDIM; ++k) {
            f = fmaf(z[k], sWf[k * C + c], f);
            s = fmaf(z[k], sWs[k * C + c], s);
        }
        float m = sigmoidf(f) * softplusf(s);
        atomicAdd(&agg[dst * C + c], m);
    }
}

// ---------------- BN stats: per-channel sum and sum-of-squares over nodes (double accum)
__global__ void __launch_bounds__(256) bn_stats_kernel(
    const float* __restrict__ agg, double* __restrict__ stats /* [2*C] */)
{
    float s[C], q[C];
    #pragma unroll
    for (int c = 0; c < C; ++c) { s[c] = 0.0f; q[c] = 0.0f; }

    for (int n = blockIdx.x * blockDim.x + threadIdx.x; n < N_NODES;
         n += gridDim.x * blockDim.x) {
        #pragma unroll
        for (int c = 0; c < C; ++c) {
            float v = agg[n * C + c];
            s[c] += v;
            q[c] += v * v;
        }
    }
    // wave(64)-level reduction
    #pragma unroll
    for (int c = 0; c < C; ++c) {
        for (int off = 32; off > 0; off >>= 1) {
            s[c] += __shfl_down(s[c], off);
            q[c] += __shfl_down(q[c], off);
        }
    }
    if ((threadIdx.x & 63) == 0) {
        #pragma unroll
        for (int c = 0; c < C; ++c) {
            atomicAdd(&stats[c], (double)s[c]);
            atomicAdd(&stats[C + c], (double)q[c]);
        }
    }
}

// ---------------- BN apply + residual: h = xin + (agg - mu) * rsqrt(var+eps) * gamma + beta
__global__ void __launch_bounds__(256) bn_apply_kernel(
    const float* __restrict__ xin, const float* __restrict__ agg,
    const double* __restrict__ stats,
    const float* __restrict__ gamma, const float* __restrict__ beta,
    float* __restrict__ hout)
{
    __shared__ float smu[C], srs[C], sg[C], sb[C];
    if (threadIdx.x < C) {
        double mu  = stats[threadIdx.x] / (double)N_NODES;
        double var = stats[C + threadIdx.x] / (double)N_NODES - mu * mu;
        smu[threadIdx.x] = (float)mu;
        srs[threadIdx.x] = (float)(1.0 / sqrt(var + (double)BN_EPS));
        sg[threadIdx.x] = gamma[threadIdx.x];
        sb[threadIdx.x] = beta[threadIdx.x];
    }
    __syncthreads();

    const int total = N_NODES * C;
    for (int i = blockIdx.x * blockDim.x + threadIdx.x; i < total;
         i += gridDim.x * blockDim.x) {
        int c = i % C;
        hout[i] = xin[i] + (agg[i] - smu[c]) * srs[c] * sg[c] + sb[c];
    }
}

// ---------------- global mean pool (accumulate)
__global__ void __launch_bounds__(256) pool_kernel(
    const float* __restrict__ h, const int* __restrict__ batch,
    float* __restrict__ gsum, float* __restrict__ gcnt)
{
    for (int n = blockIdx.x * blockDim.x + threadIdx.x; n < N_NODES;
         n += gridDim.x * blockDim.x) {
        int g = batch[n];
        #pragma unroll
        for (int c = 0; c < C; ++c) atomicAdd(&gsum[g * C + c], h[n * C + c]);
        atomicAdd(&gcnt[g], 1.0f);
    }
}

// ---------------- MLP head: out = softplus(pooled @ W1 + b1) @ W2 + b2
__global__ void __launch_bounds__(256) head_kernel(
    const float* __restrict__ gsum, const float* __restrict__ gcnt,
    const float* __restrict__ W1, const float* __restrict__ b1,
    const float* __restrict__ W2, const float* __restrict__ b2,
    float* __restrict__ out)
{
    int g = blockIdx.x * blockDim.x + threadIdx.x;
    if (g >= N_GRAPHS) return;
    float cnt = fmaxf(gcnt[g], 1.0f);
    float p[C];
    #pragma unroll
    for (int c = 0; c < C; ++c) p[c] = gsum[g * C + c] / cnt;
    float acc = b2[0];
    #pragma unroll
    for (int j = 0; j < 5; ++j) {
        float t = b1[j];
        #pragma unroll
        for (int c = 0; c < C; ++c) t = fmaf(p[c], W1[c * 5 + j], t);
        acc = fmaf(softplusf(t), W2[j], acc);
    }
    out[g] = acc;
}

extern "C" void kernel_launch(void* const* d_in, const int* in_sizes, int n_in,
                              void* d_out, int out_size, void* d_ws, size_t ws_size,
                              hipStream_t stream) {
    const float* x   = (const float*)d_in[0];
    const int*   ei  = (const int*)d_in[1];
    const float* ea  = (const float*)d_in[2];
    const int*   bat = (const int*)d_in[3];
    const float* Wf1 = (const float*)d_in[4];
    const float* bf1 = (const float*)d_in[5];
    const float* Ws1 = (const float*)d_in[6];
    const float* bs1 = (const float*)d_in[7];
    const float* g1  = (const float*)d_in[8];
    const float* be1 = (const float*)d_in[9];
    const float* Wf2 = (const float*)d_in[10];
    const float* bf2 = (const float*)d_in[11];
    const float* Ws2 = (const float*)d_in[12];
    const float* bs2 = (const float*)d_in[13];
    const float* g2  = (const float*)d_in[14];
    const float* be2 = (const float*)d_in[15];
    const float* W_fc1 = (const float*)d_in[16];
    const float* b_fc1 = (const float*)d_in[17];
    const float* W_fc2 = (const float*)d_in[18];
    const float* b_fc2 = (const float*)d_in[19];
    float* out = (float*)d_out;

    // workspace layout (bytes)
    char* ws = (char*)d_ws;
    float*  agg   = (float*)(ws);                                   // N*C floats
    float*  h     = (float*)(ws + (size_t)N_NODES * C * 4);         // N*C floats
    double* stats = (double*)(ws + (size_t)2 * N_NODES * C * 4);    // 2*C doubles
    float*  gsum  = (float*)(ws + (size_t)2 * N_NODES * C * 4 + 2 * C * 8); // G*C floats
    float*  gcnt  = (float*)((char*)gsum + (size_t)N_GRAPHS * C * 4);        // G floats

    const int eblocks = (N_EDGES + 255) / 256;
    const int nblocks = 256;   // grid-stride kernels over nodes

    // -------- layer 1
    hipMemsetAsync(agg, 0, (size_t)N_NODES * C * 4, stream);
    hipMemsetAsync(stats, 0, 2 * C * 8, stream);
    edge_kernel<<<eblocks, 256, 0, stream>>>(x, ei, ea, Wf1, bf1, Ws1, bs1, agg);
    bn_stats_kernel<<<nblocks, 256, 0, stream>>>(agg, stats);
    bn_apply_kernel<<<512, 256, 0, stream>>>(x, agg, stats, g1, be1, h);

    // -------- layer 2
    hipMemsetAsync(agg, 0, (size_t)N_NODES * C * 4, stream);
    hipMemsetAsync(stats, 0, 2 * C * 8, stream);
    edge_kernel<<<eblocks, 256, 0, stream>>>(h, ei, ea, Wf2, bf2, Ws2, bs2, agg);
    bn_stats_kernel<<<nblocks, 256, 0, stream>>>(agg, stats);
    bn_apply_kernel<<<512, 256, 0, stream>>>(h, agg, stats, g2, be2, h);

    // -------- pool + head
    hipMemsetAsync(gsum, 0, (size_t)N_GRAPHS * C * 4 + (size_t)N_GRAPHS * 4, stream);
    pool_kernel<<<nblocks, 256, 0, stream>>>(h, bat, gsum, gcnt);
    head_kernel<<<(N_GRAPHS + 255) / 256, 256, 0, stream>>>(gsum, gcnt, W_fc1, b_fc1,
                                                            W_fc2, b_fc2, out);
}

// Round 2
// 1672.772 us; speedup vs baseline: 2.3693x; 2.3693x over previous
//
#include <hip/hip_runtime.h>
#include <math.h>

#define N_NODES 100000
#define N_EDGES 3200000
#define N_GRAPHS 1000
#define C 11
#define D 4
#define ZDIM (2*C + D)   // 26
#define BN_EPS 1e-5f

__device__ __forceinline__ float softplusf(float x) {
    return (x > 20.0f) ? x : log1pf(expf(x));
}
__device__ __forceinline__ float sigmoidf(float x) {
    return 1.0f / (1.0f + expf(-x));
}

// ============ CSR build ============

__global__ void __launch_bounds__(256) hist_kernel(
    const int* __restrict__ ei, int* __restrict__ deg)
{
    int e = blockIdx.x * blockDim.x + threadIdx.x;
    if (e < N_EDGES) atomicAdd(&deg[ei[N_EDGES + e]], 1);
}

// single-block exclusive scan: off[0]=0, off[i+1] = sum deg[0..i]
__global__ void __launch_bounds__(1024) scan_kernel(
    const int* __restrict__ deg, int* __restrict__ off)
{
    __shared__ int wsum[16];
    __shared__ int carry_s;
    if (threadIdx.x == 0) { carry_s = 0; off[0] = 0; }
    __syncthreads();
    int lane = threadIdx.x & 63, wid = threadIdx.x >> 6;
    for (int base = 0; base < N_NODES; base += 1024) {
        int i = base + threadIdx.x;
        int v = (i < N_NODES) ? deg[i] : 0;
        int s = v;
        #pragma unroll
        for (int d = 1; d < 64; d <<= 1) {
            int t = __shfl_up(s, d);
            if (lane >= d) s += t;
        }
        if (lane == 63) wsum[wid] = s;
        __syncthreads();
        if (wid == 0) {
            int w = (lane < 16) ? wsum[lane] : 0;
            #pragma unroll
            for (int d = 1; d < 16; d <<= 1) {
                int t = __shfl_up(w, d);
                if (lane >= d) w += t;
            }
            if (lane < 16) wsum[lane] = w;
        }
        __syncthreads();
        int add = carry_s + (wid > 0 ? wsum[wid - 1] : 0);
        if (i < N_NODES) off[i + 1] = add + s;
        __syncthreads();
        if (threadIdx.x == 0) carry_s += wsum[15];
        __syncthreads();
    }
}

// scatter edges into CSR buckets; reorder edge_attr alongside
__global__ void __launch_bounds__(256) scatter_kernel(
    const int* __restrict__ ei, const float4* __restrict__ ea,
    const int* __restrict__ off, int* __restrict__ cursor,
    int* __restrict__ src_csr, float4* __restrict__ ea_csr)
{
    int e = blockIdx.x * blockDim.x + threadIdx.x;
    if (e >= N_EDGES) return;
    int src = ei[e];
    int dst = ei[N_EDGES + e];
    int pos = off[dst] + atomicAdd(&cursor[dst], 1);
    src_csr[pos] = src;
    ea_csr[pos] = ea[e];
}

// ============ CGConv gather: 4 lanes per node ============

__global__ void __launch_bounds__(256) conv_kernel(
    const float* __restrict__ x,
    const int* __restrict__ off, const int* __restrict__ src_csr,
    const float4* __restrict__ ea_csr,
    const float* __restrict__ Wf, const float* __restrict__ bf,
    const float* __restrict__ Ws, const float* __restrict__ bs,
    float* __restrict__ agg)
{
    __shared__ float sWf[ZDIM * C];
    __shared__ float sWs[ZDIM * C];
    __shared__ float sbf[C];
    __shared__ float sbs[C];
    for (int i = threadIdx.x; i < ZDIM * C; i += blockDim.x) {
        sWf[i] = Wf[i];
        sWs[i] = Ws[i];
    }
    if (threadIdx.x < C) { sbf[threadIdx.x] = bf[threadIdx.x]; sbs[threadIdx.x] = bs[threadIdx.x]; }
    __syncthreads();

    int tid = blockIdx.x * blockDim.x + threadIdx.x;
    int n = tid >> 2;         // 4 threads per node
    int t = tid & 3;
    if (n >= N_NODES) return;

    // hoist x_i contribution: basef/bases[c] = b[c] + sum_j xi[j]*W[j][c]
    float xi[C];
    #pragma unroll
    for (int j = 0; j < C; ++j) xi[j] = x[n * C + j];
    float basef[C], bases[C];
    #pragma unroll
    for (int c = 0; c < C; ++c) {
        float f = sbf[c], s = sbs[c];
        #pragma unroll
        for (int j = 0; j < C; ++j) {
            f = fmaf(xi[j], sWf[j * C + c], f);
            s = fmaf(xi[j], sWs[j * C + c], s);
        }
        basef[c] = f; bases[c] = s;
    }

    float acc[C];
    #pragma unroll
    for (int c = 0; c < C; ++c) acc[c] = 0.0f;

    int e0 = off[n], e1 = off[n + 1];
    for (int k = e0 + t; k < e1; k += 4) {
        int srcn = src_csr[k];
        float4 eav = ea_csr[k];
        float xj[C];
        #pragma unroll
        for (int j = 0; j < C; ++j) xj[j] = x[srcn * C + j];
        #pragma unroll
        for (int c = 0; c < C; ++c) {
            float f = basef[c], s = bases[c];
            #pragma unroll
            for (int j = 0; j < C; ++j) {
                f = fmaf(xj[j], sWf[(C + j) * C + c], f);
                s = fmaf(xj[j], sWs[(C + j) * C + c], s);
            }
            f = fmaf(eav.x, sWf[(2 * C + 0) * C + c], f);
            s = fmaf(eav.x, sWs[(2 * C + 0) * C + c], s);
            f = fmaf(eav.y, sWf[(2 * C + 1) * C + c], f);
            s = fmaf(eav.y, sWs[(2 * C + 1) * C + c], s);
            f = fmaf(eav.z, sWf[(2 * C + 2) * C + c], f);
            s = fmaf(eav.z, sWs[(2 * C + 2) * C + c], s);
            f = fmaf(eav.w, sWf[(2 * C + 3) * C + c], f);
            s = fmaf(eav.w, sWs[(2 * C + 3) * C + c], s);
            acc[c] += sigmoidf(f) * softplusf(s);
        }
    }

    // combine the 4 lanes of this node (lanes n*4..n*4+3 are in the same wave)
    #pragma unroll
    for (int c = 0; c < C; ++c) {
        acc[c] += __shfl_xor(acc[c], 1);
        acc[c] += __shfl_xor(acc[c], 2);
    }
    if (t == 0) {
        #pragma unroll
        for (int c = 0; c < C; ++c) agg[n * C + c] = acc[c];
    }
}

// ============ BatchNorm ============

__global__ void __launch_bounds__(256) bn_stats_kernel(
    const float* __restrict__ agg, double* __restrict__ stats /* [2*C] */)
{
    float s[C], q[C];
    #pragma unroll
    for (int c = 0; c < C; ++c) { s[c] = 0.0f; q[c] = 0.0f; }

    for (int n = blockIdx.x * blockDim.x + threadIdx.x; n < N_NODES;
         n += gridDim.x * blockDim.x) {
        #pragma unroll
        for (int c = 0; c < C; ++c) {
            float v = agg[n * C + c];
            s[c] += v;
            q[c] += v * v;
        }
    }
    #pragma unroll
    for (int c = 0; c < C; ++c) {
        for (int off = 32; off > 0; off >>= 1) {
            s[c] += __shfl_down(s[c], off);
            q[c] += __shfl_down(q[c], off);
        }
    }
    if ((threadIdx.x & 63) == 0) {
        #pragma unroll
        for (int c = 0; c < C; ++c) {
            atomicAdd(&stats[c], (double)s[c]);
            atomicAdd(&stats[C + c], (double)q[c]);
        }
    }
}

__global__ void __launch_bounds__(256) bn_apply_kernel(
    const float* __restrict__ xin, const float* __restrict__ agg,
    const double* __restrict__ stats,
    const float* __restrict__ gamma, const float* __restrict__ beta,
    float* __restrict__ hout)
{
    __shared__ float smu[C], srs[C], sg[C], sb[C];
    if (threadIdx.x < C) {
        double mu  = stats[threadIdx.x] / (double)N_NODES;
        double var = stats[C + threadIdx.x] / (double)N_NODES - mu * mu;
        smu[threadIdx.x] = (float)mu;
        srs[threadIdx.x] = (float)(1.0 / sqrt(var + (double)BN_EPS));
        sg[threadIdx.x] = gamma[threadIdx.x];
        sb[threadIdx.x] = beta[threadIdx.x];
    }
    __syncthreads();

    const int total = N_NODES * C;
    for (int i = blockIdx.x * blockDim.x + threadIdx.x; i < total;
         i += gridDim.x * blockDim.x) {
        int c = i % C;
        hout[i] = xin[i] + (agg[i] - smu[c]) * srs[c] * sg[c] + sb[c];
    }
}

// ============ pool (batch is sorted) + head ============

__global__ void __launch_bounds__(256) pool_kernel(
    const float* __restrict__ h, const int* __restrict__ batch,
    float* __restrict__ gsum, float* __restrict__ gcnt)
{
    const int PER = 8;
    int t = blockIdx.x * blockDim.x + threadIdx.x;
    int start = t * PER;
    if (start >= N_NODES) return;
    int end = min(start + PER, N_NODES);

    int g = batch[start];
    float acc[C];
    #pragma unroll
    for (int c = 0; c < C; ++c) acc[c] = 0.0f;
    float cnt = 0.0f;

    for (int n = start; n < end; ++n) {
        int gn = batch[n];
        if (gn != g) {
            #pragma unroll
            for (int c = 0; c < C; ++c) atomicAdd(&gsum[g * C + c], acc[c]);
            atomicAdd(&gcnt[g], cnt);
            g = gn;
            #pragma unroll
            for (int c = 0; c < C; ++c) acc[c] = 0.0f;
            cnt = 0.0f;
        }
        #pragma unroll
        for (int c = 0; c < C; ++c) acc[c] += h[n * C + c];
        cnt += 1.0f;
    }
    #pragma unroll
    for (int c = 0; c < C; ++c) atomicAdd(&gsum[g * C + c], acc[c]);
    atomicAdd(&gcnt[g], cnt);
}

__global__ void __launch_bounds__(256) head_kernel(
    const float* __restrict__ gsum, const float* __restrict__ gcnt,
    const float* __restrict__ W1, const float* __restrict__ b1,
    const float* __restrict__ W2, const float* __restrict__ b2,
    float* __restrict__ out)
{
    int g = blockIdx.x * blockDim.x + threadIdx.x;
    if (g >= N_GRAPHS) return;
    float cnt = fmaxf(gcnt[g], 1.0f);
    float p[C];
    #pragma unroll
    for (int c = 0; c < C; ++c) p[c] = gsum[g * C + c] / cnt;
    float acc = b2[0];
    #pragma unroll
    for (int j = 0; j < 5; ++j) {
        float t = b1[j];
        #pragma unroll
        for (int c = 0; c < C; ++c) t = fmaf(p[c], W1[c * 5 + j], t);
        acc = fmaf(softplusf(t), W2[j], acc);
    }
    out[g] = acc;
}

extern "C" void kernel_launch(void* const* d_in, const int* in_sizes, int n_in,
                              void* d_out, int out_size, void* d_ws, size_t ws_size,
                              hipStream_t stream) {
    const float* x   = (const float*)d_in[0];
    const int*   ei  = (const int*)d_in[1];
    const float* ea  = (const float*)d_in[2];
    const int*   bat = (const int*)d_in[3];
    const float* Wf1 = (const float*)d_in[4];
    const float* bf1 = (const float*)d_in[5];
    const float* Ws1 = (const float*)d_in[6];
    const float* bs1 = (const float*)d_in[7];
    const float* g1  = (const float*)d_in[8];
    const float* be1 = (const float*)d_in[9];
    const float* Wf2 = (const float*)d_in[10];
    const float* bf2 = (const float*)d_in[11];
    const float* Ws2 = (const float*)d_in[12];
    const float* bs2 = (const float*)d_in[13];
    const float* g2  = (const float*)d_in[14];
    const float* be2 = (const float*)d_in[15];
    const float* W_fc1 = (const float*)d_in[16];
    const float* b_fc1 = (const float*)d_in[17];
    const float* W_fc2 = (const float*)d_in[18];
    const float* b_fc2 = (const float*)d_in[19];
    float* out = (float*)d_out;

    // ---- workspace layout (bytes) ----
    char* ws = (char*)d_ws;
    size_t o = 0;
    int*    deg     = (int*)(ws + o);    o += (size_t)N_NODES * 4;        // also reused as cursor
    int*    cursor  = (int*)(ws + o);    o += (size_t)N_NODES * 4;
    int*    off     = (int*)(ws + o);    o += (size_t)(N_NODES + 1) * 4;
    o = (o + 255) & ~(size_t)255;
    int*    src_csr = (int*)(ws + o);    o += (size_t)N_EDGES * 4;
    o = (o + 255) & ~(size_t)255;
    float4* ea_csr  = (float4*)(ws + o); o += (size_t)N_EDGES * 16;
    float*  agg     = (float*)(ws + o);  o += (size_t)N_NODES * C * 4;
    float*  h       = (float*)(ws + o);  o += (size_t)N_NODES * C * 4;
    double* stats   = (double*)(ws + o); o += 2 * C * 8;
    float*  gsum    = (float*)(ws + o);  o += (size_t)N_GRAPHS * C * 4;
    float*  gcnt    = (float*)(ws + o);  o += (size_t)N_GRAPHS * 4;

    const int eblocks = (N_EDGES + 255) / 256;
    const int cblocks = (N_NODES * 4 + 255) / 256;

    // ---- CSR build (shared by both layers) ----
    hipMemsetAsync(deg, 0, (size_t)N_NODES * 4, stream);
    hist_kernel<<<eblocks, 256, 0, stream>>>(ei, deg);
    scan_kernel<<<1, 1024, 0, stream>>>(deg, off);
    hipMemsetAsync(cursor, 0, (size_t)N_NODES * 4, stream);
    scatter_kernel<<<eblocks, 256, 0, stream>>>(ei, (const float4*)ea, off, cursor,
                                                src_csr, ea_csr);

    // ---- layer 1 ----
    hipMemsetAsync(stats, 0, 2 * C * 8, stream);
    conv_kernel<<<cblocks, 256, 0, stream>>>(x, off, src_csr, ea_csr,
                                             Wf1, bf1, Ws1, bs1, agg);
    bn_stats_kernel<<<256, 256, 0, stream>>>(agg, stats);
    bn_apply_kernel<<<512, 256, 0, stream>>>(x, agg, stats, g1, be1, h);

    // ---- layer 2 ----
    hipMemsetAsync(stats, 0, 2 * C * 8, stream);
    conv_kernel<<<cblocks, 256, 0, stream>>>(h, off, src_csr, ea_csr,
                                             Wf2, bf2, Ws2, bs2, agg);
    bn_stats_kernel<<<256, 256, 0, stream>>>(agg, stats);
    bn_apply_kernel<<<512, 256, 0, stream>>>(h, agg, stats, g2, be2, h);

    // ---- pool + head ----
    hipMemsetAsync(gsum, 0, (size_t)N_GRAPHS * (C + 1) * 4, stream);
    pool_kernel<<<(N_NODES / 8 + 255) / 256, 256, 0, stream>>>(h, bat, gsum, gcnt);
    head_kernel<<<(N_GRAPHS + 255) / 256, 256, 0, stream>>>(gsum, gcnt, W_fc1, b_fc1,
                                                            W_fc2, b_fc2, out);
}